// Round 5
// baseline (217.594 us; speedup 1.0000x reference)
//
#include <hip/hip_runtime.h>
#include <cstdint>
#include <cstddef>

typedef unsigned short ushort_t;
typedef unsigned int uint_t;

typedef __bf16 bf16x8 __attribute__((ext_vector_type(8)));
typedef float floatx4 __attribute__((ext_vector_type(4)));

#define B_ 16
#define N1_ 4096
#define N2_ 1024
#define C1_ 128
#define C2_ 256
#define DIN_ 384
#define DOUT_ 256
#define M_ (B_ * N1_)  // 65536

// ---------------- helpers ----------------

__device__ __forceinline__ ushort_t f2bf(float f) {
  unsigned int u = __builtin_bit_cast(unsigned int, f);
  u = (u + 0x7fffu + ((u >> 16) & 1u)) >> 16;  // RNE
  return (ushort_t)u;
}

// As chunk swizzle: XOR the 16B-chunk bits (3-4 of the ushort kk index) with
// (row>>1)&3. Writer granules (8B interp / 4B feat1) stay inside one chunk;
// reader's b128 reads one whole permuted chunk. Makes each 8-lane phase of a
// ds_read_b128 cover 8 distinct 16B ranges -> conflict-free (was 4-way).
#define AS_IDX(t, row, kk) \
  ((t) * 2048 + (row) * 32 + ((kk) ^ ((((row) >> 1) & 3) << 3)))

// ---------------- kernel P: weight swizzle + bf16 convert ----------------
// W1s[t][n][kk] = bf16(W1[t*32+kk][n]), t=0..11, n=0..255, kk=0..31

__global__ __launch_bounds__(256) void prep_kernel(
    const float* __restrict__ W1, const float* __restrict__ W2,
    ushort_t* __restrict__ W1s, ushort_t* __restrict__ W2s) {
  int e = blockIdx.x * 256 + threadIdx.x;
  if (e < DOUT_ * DIN_) {  // 98304
    int kk = e & 31, n = (e >> 5) & 255, t = e >> 13;
    W1s[e] = f2bf(W1[(size_t)(t * 32 + kk) * DOUT_ + n]);
  }
  if (e < DOUT_ * DOUT_) {  // 65536
    int kk = e & 31, n = (e >> 5) & 255, t = e >> 13;
    W2s[e] = f2bf(W2[(size_t)(t * 32 + kk) * DOUT_ + n]);
  }
}

// ---------------- kernel A: 3-NN + inverse-distance weights ----------------
// 4 rows per thread (rows g, g+16, g+32, g+48 of a 64-row block), 8 subs/row.
// One xs4 LDS read feeds FOUR independent insert chains -> issue-saturated
// VALU (68 ops per ds_read, 4 independent dep chains) at 2 waves/SIMD.
// Scan order (p = sub + 8t) and merge sequence byte-identical to verified.

__device__ __forceinline__ void ins_exact(float& s0, float& s1, float& s2,
                                          int& i0, int& i1, int& i2,
                                          float d, int p) {
  float ns2 = __builtin_amdgcn_fmed3f(d, s1, s2);
  float ns1 = __builtin_amdgcn_fmed3f(d, s0, s1);
  float ns0 = fminf(d, s0);
  bool c0 = d < s0, c1 = d < s1, c2 = d < s2;
  i2 = c1 ? i1 : (c2 ? p : i2);
  i1 = c0 ? i0 : (c1 ? p : i1);
  i0 = c0 ? p : i0;
  s0 = ns0; s1 = ns1; s2 = ns2;
}

__device__ __forceinline__ void ins_merge(float& s0, float& s1, float& s2,
                                          int& i0, int& i1, int& i2,
                                          float e, int j) {
  bool t0 = (e < s0) || (e == s0 && j < i0);
  bool t1 = (e < s1) || (e == s1 && j < i1);
  bool t2 = (e < s2) || (e == s2 && j < i2);
  s2 = t1 ? s1 : (t2 ? e : s2);
  i2 = t1 ? i1 : (t2 ? j : i2);
  s1 = t0 ? s0 : (t1 ? e : s1);
  i1 = t0 ? i0 : (t1 ? j : i1);
  s0 = t0 ? e : s0;
  i0 = t0 ? j : i0;
}

__global__ __launch_bounds__(128) void knn_kernel(
    const float* __restrict__ xyz1, const float* __restrict__ xyz2,
    int* __restrict__ idx_out, float* __restrict__ w_out) {
  __shared__ float4 xs4[N2_];  // 16 KB
  int b = blockIdx.x >> 6;              // 64 blocks per batch
  int n1base = (blockIdx.x & 63) << 6;  // 64 rows per block
  const float* p2 = xyz2 + (size_t)b * N2_ * 3;
  for (int i = threadIdx.x; i < N2_; i += 128) {
    const float* s = p2 + 3 * i;
    xs4[i] = make_float4(s[0], s[1], s[2], 0.0f);
  }
  __syncthreads();

  int g = threadIdx.x >> 3;  // 0..15 -> rows {g, g+16, g+32, g+48}
  int sub = threadIdx.x & 7;

  float px[4], py[4], pz[4];
  float s0[4], s1[4], s2[4];
  int i0[4], i1[4], i2[4];
#pragma unroll
  for (int r = 0; r < 4; ++r) {
    int row = b * N1_ + n1base + g + 16 * r;
    const float* p1 = xyz1 + (size_t)row * 3;
    px[r] = p1[0]; py[r] = p1[1]; pz[r] = p1[2];
    s0[r] = 3.0e38f; s1[r] = 3.0e38f; s2[r] = 3.0e38f;
    i0[r] = 0; i1[r] = 0; i2[r] = 0;
  }

  int p = sub;
#pragma unroll 4
  for (int t = 0; t < N2_ / 8; ++t) {
    float4 qv = xs4[p];
#pragma unroll
    for (int r = 0; r < 4; ++r) {
      float dx = px[r] - qv.x, dy = py[r] - qv.y, dz = pz[r] - qv.z;
      float d = dx * dx + dy * dy + dz * dz;
      ins_exact(s0[r], s1[r], s2[r], i0[r], i1[r], i2[r], d, p);
    }
    p += 8;
  }

#pragma unroll
  for (int mm = 1; mm <= 4; mm <<= 1) {
#pragma unroll
    for (int r = 0; r < 4; ++r) {
      float e0 = __shfl_xor(s0[r], mm), e1 = __shfl_xor(s1[r], mm), e2 = __shfl_xor(s2[r], mm);
      int j0 = __shfl_xor(i0[r], mm), j1 = __shfl_xor(i1[r], mm), j2 = __shfl_xor(i2[r], mm);
      ins_merge(s0[r], s1[r], s2[r], i0[r], i1[r], i2[r], e0, j0);
      ins_merge(s0[r], s1[r], s2[r], i0[r], i1[r], i2[r], e1, j1);
      ins_merge(s0[r], s1[r], s2[r], i0[r], i1[r], i2[r], e2, j2);
    }
  }

  if (sub == 0) {
#pragma unroll
    for (int r = 0; r < 4; ++r) {
      int row = b * N1_ + n1base + g + 16 * r;
      float r0 = 1.0f / fmaxf(s0[r], 1e-10f);
      float r1 = 1.0f / fmaxf(s1[r], 1e-10f);
      float r2 = 1.0f / fmaxf(s2[r], 1e-10f);
      float s = 1.0f / (r0 + r1 + r2);
      int base = row * 3;
      idx_out[base + 0] = i0[r];
      idx_out[base + 1] = i1[r];
      idx_out[base + 2] = i2[r];
      w_out[base + 0] = r0 * s;
      w_out[base + 1] = r1 * s;
      w_out[base + 2] = r2 * s;
    }
  }
}

// ---------------- fused: build + GEMM1 + GEMM2 ----------------
// 64 rows/block, 1024 blocks, 256 threads (4 waves; wave w owns col-quarter
// [64w, 64w+64) of both GEMMs). Changes vs verified 61 us baseline:
//  (a) As chunk-XOR swizzle (AS_IDX) -> GEMM1 a-frag ds_read_b128 goes
//      4-way-conflicted -> conflict-free (HS/GEMM2 already swizzled).
//  (b) Quad-buffered W-fragment prefetch: W frags issued 2 t-steps (~280cy)
//      ahead of use (> L2 latency), vs 1 step (~160cy) before. First two W1
//      t-steps are issued at kernel top so they land during the build phase.

__global__ __launch_bounds__(256, 2) void fused_kernel(
    const float* __restrict__ feat1, const float* __restrict__ feat2,
    const int* __restrict__ idx, const float* __restrict__ w,
    const ushort_t* __restrict__ W1s, const float* __restrict__ b1,
    const ushort_t* __restrict__ W2s, const float* __restrict__ b2,
    float* __restrict__ out) {
  __shared__ ushort_t As[64 * 384];  // 48 KB; HS (64x256 = 32 KB) aliases front
  const int tid = threadIdx.x;
  const int wave = tid >> 6;
  const int lane = tid & 63;
  const int m = lane & 15;
  const int q = lane >> 4;
  const int row0 = blockIdx.x * 64;
  const int b = row0 >> 12;

  const int b_off = (wave * 64 + m) * 32 + q * 8;  // frag base in W1s/W2s tile

  // W quad-buffers (shared between GEMM1 and GEMM2 phases)
  bf16x8 w0[4], w1[4], w2[4], w3[4], af[4];

  // issue W1 t=0,1 frags now; they complete under the build phase
#pragma unroll
  for (int j = 0; j < 4; ++j) {
    w0[j] = *(const bf16x8*)(W1s + b_off + j * 512);
    w1[j] = *(const bf16x8*)(W1s + 8192 + b_off + j * 512);
  }

  // ---- build phase: As[t][row][kk-swz] (t = k/32), bf16 ----
#pragma unroll 4
  for (int it = 0; it < 16; ++it) {
    int rl = wave * 16 + it;
    int row = row0 + rl;
    const int* ip = idx + (size_t)row * 3;
    const float* wp = w + (size_t)row * 3;
    int i0 = ip[0], i1 = ip[1], i2 = ip[2];
    float w0v = wp[0], w1v = wp[1], w2v = wp[2];

    const float4* f0 = (const float4*)(feat2 + ((size_t)b * N2_ + i0) * C2_);
    const float4* f1 = (const float4*)(feat2 + ((size_t)b * N2_ + i1) * C2_);
    const float4* f2 = (const float4*)(feat2 + ((size_t)b * N2_ + i2) * C2_);
    float4 a = f0[lane];
    float4 c = f1[lane];
    float4 d = f2[lane];
    float vx = w0v * a.x + w1v * c.x + w2v * d.x;
    float vy = w0v * a.y + w1v * c.y + w2v * d.y;
    float vz = w0v * a.z + w1v * c.z + w2v * d.z;
    float vw = w0v * a.w + w1v * c.w + w2v * d.w;
    // cols 4*lane .. 4*lane+3 (8B granule, stays inside one 16B chunk)
    uint_t lo = (uint_t)f2bf(vx) | ((uint_t)f2bf(vy) << 16);
    uint_t hi = (uint_t)f2bf(vz) | ((uint_t)f2bf(vw) << 16);
    int e = AS_IDX(lane >> 3, rl, (4 * lane) & 31);
    *(uint2*)&As[e] = make_uint2(lo, hi);

    // feat1: cols 256 + 2*lane, 2*lane+1 (4B granule)
    float2 t1 = ((const float2*)(feat1 + (size_t)row * C1_))[lane];
    uint_t pk = (uint_t)f2bf(t1.x) | ((uint_t)f2bf(t1.y) << 16);
    int e1 = AS_IDX(8 + (lane >> 4), rl, (2 * lane) & 31);
    *(uint_t*)&As[e1] = pk;
  }
  __syncthreads();

  // ---- GEMM1: K = 384 (12 t-steps), quad-buffered W prefetch ----
  floatx4 acc[4][4];
#pragma unroll
  for (int i = 0; i < 4; ++i)
#pragma unroll
    for (int j = 0; j < 4; ++j) acc[i][j] = (floatx4)0.0f;

#pragma unroll
  for (int tt = 0; tt < 12; tt += 4) {
#pragma unroll
    for (int j = 0; j < 4; ++j) {
      w2[j] = *(const bf16x8*)(W1s + (size_t)(tt + 2) * 8192 + b_off + j * 512);
      w3[j] = *(const bf16x8*)(W1s + (size_t)(tt + 3) * 8192 + b_off + j * 512);
    }
#pragma unroll
    for (int i = 0; i < 4; ++i)
      af[i] = *(const bf16x8*)&As[AS_IDX(tt, m + 16 * i, q * 8)];
#pragma unroll
    for (int i = 0; i < 4; ++i)
#pragma unroll
      for (int j = 0; j < 4; ++j)
        acc[i][j] = __builtin_amdgcn_mfma_f32_16x16x32_bf16(af[i], w0[j],
                                                            acc[i][j], 0, 0, 0);
#pragma unroll
    for (int i = 0; i < 4; ++i)
      af[i] = *(const bf16x8*)&As[AS_IDX(tt + 1, m + 16 * i, q * 8)];
#pragma unroll
    for (int i = 0; i < 4; ++i)
#pragma unroll
      for (int j = 0; j < 4; ++j)
        acc[i][j] = __builtin_amdgcn_mfma_f32_16x16x32_bf16(af[i], w1[j],
                                                            acc[i][j], 0, 0, 0);
    if (tt + 4 < 12) {
#pragma unroll
      for (int j = 0; j < 4; ++j) {
        w0[j] = *(const bf16x8*)(W1s + (size_t)(tt + 4) * 8192 + b_off + j * 512);
        w1[j] = *(const bf16x8*)(W1s + (size_t)(tt + 5) * 8192 + b_off + j * 512);
      }
    }
#pragma unroll
    for (int i = 0; i < 4; ++i)
      af[i] = *(const bf16x8*)&As[AS_IDX(tt + 2, m + 16 * i, q * 8)];
#pragma unroll
    for (int i = 0; i < 4; ++i)
#pragma unroll
      for (int j = 0; j < 4; ++j)
        acc[i][j] = __builtin_amdgcn_mfma_f32_16x16x32_bf16(af[i], w2[j],
                                                            acc[i][j], 0, 0, 0);
#pragma unroll
    for (int i = 0; i < 4; ++i)
      af[i] = *(const bf16x8*)&As[AS_IDX(tt + 3, m + 16 * i, q * 8)];
#pragma unroll
    for (int i = 0; i < 4; ++i)
#pragma unroll
      for (int j = 0; j < 4; ++j)
        acc[i][j] = __builtin_amdgcn_mfma_f32_16x16x32_bf16(af[i], w3[j],
                                                            acc[i][j], 0, 0, 0);
  }

  // issue W2 t=0,1 frags now; they complete under epilogue1
#pragma unroll
  for (int j = 0; j < 4; ++j) {
    w0[j] = *(const bf16x8*)(W2s + b_off + j * 512);
    w1[j] = *(const bf16x8*)(W2s + 8192 + b_off + j * 512);
  }
  __syncthreads();  // all As reads done before HS overwrites the region

  // ---- epilogue1: bias + relu -> bf16 HS (aliases As; XOR-chunk swizzle) ----
  ushort_t* HS = As;  // 64 x 256 = 16384 elems
#pragma unroll
  for (int j = 0; j < 4; ++j) {
    int col = wave * 64 + j * 16 + m;
    float bv = b1[col];
    int cb = (col >> 3) & 3;
    int tb = (col >> 5) * 2048 + (col & 7);
#pragma unroll
    for (int i = 0; i < 4; ++i)
#pragma unroll
      for (int r = 0; r < 4; ++r) {
        int row = i * 16 + q * 4 + r;
        float v = acc[i][j][r] + bv;
        v = v > 0.0f ? v : 0.0f;
        int ch = cb ^ ((row >> 2) & 3);
        HS[tb + row * 32 + ch * 8] = f2bf(v);
      }
  }
  __syncthreads();

  // ---- GEMM2: K = 256 (8 t-steps), a-frags from HS, quad-buffered W ----
  floatx4 acc2[4][4];
#pragma unroll
  for (int i = 0; i < 4; ++i)
#pragma unroll
    for (int j = 0; j < 4; ++j) acc2[i][j] = (floatx4)0.0f;

#pragma unroll
  for (int tt = 0; tt < 8; tt += 4) {
#pragma unroll
    for (int j = 0; j < 4; ++j) {
      w2[j] = *(const bf16x8*)(W2s + (size_t)(tt + 2) * 8192 + b_off + j * 512);
      w3[j] = *(const bf16x8*)(W2s + (size_t)(tt + 3) * 8192 + b_off + j * 512);
    }
#pragma unroll
    for (int i = 0; i < 4; ++i) {
      int row = m + 16 * i;
      int ch = q ^ ((row >> 2) & 3);
      af[i] = *(const bf16x8*)&HS[tt * 2048 + row * 32 + ch * 8];
    }
#pragma unroll
    for (int i = 0; i < 4; ++i)
#pragma unroll
      for (int j = 0; j < 4; ++j)
        acc2[i][j] = __builtin_amdgcn_mfma_f32_16x16x32_bf16(af[i], w0[j],
                                                             acc2[i][j], 0, 0, 0);
#pragma unroll
    for (int i = 0; i < 4; ++i) {
      int row = m + 16 * i;
      int ch = q ^ ((row >> 2) & 3);
      af[i] = *(const bf16x8*)&HS[(tt + 1) * 2048 + row * 32 + ch * 8];
    }
#pragma unroll
    for (int i = 0; i < 4; ++i)
#pragma unroll
      for (int j = 0; j < 4; ++j)
        acc2[i][j] = __builtin_amdgcn_mfma_f32_16x16x32_bf16(af[i], w1[j],
                                                             acc2[i][j], 0, 0, 0);
    if (tt + 4 < 8) {
#pragma unroll
      for (int j = 0; j < 4; ++j) {
        w0[j] = *(const bf16x8*)(W2s + (size_t)(tt + 4) * 8192 + b_off + j * 512);
        w1[j] = *(const bf16x8*)(W2s + (size_t)(tt + 5) * 8192 + b_off + j * 512);
      }
    }
#pragma unroll
    for (int i = 0; i < 4; ++i) {
      int row = m + 16 * i;
      int ch = q ^ ((row >> 2) & 3);
      af[i] = *(const bf16x8*)&HS[(tt + 2) * 2048 + row * 32 + ch * 8];
    }
#pragma unroll
    for (int i = 0; i < 4; ++i)
#pragma unroll
      for (int j = 0; j < 4; ++j)
        acc2[i][j] = __builtin_amdgcn_mfma_f32_16x16x32_bf16(af[i], w2[j],
                                                             acc2[i][j], 0, 0, 0);
#pragma unroll
    for (int i = 0; i < 4; ++i) {
      int row = m + 16 * i;
      int ch = q ^ ((row >> 2) & 3);
      af[i] = *(const bf16x8*)&HS[(tt + 3) * 2048 + row * 32 + ch * 8];
    }
#pragma unroll
    for (int i = 0; i < 4; ++i)
#pragma unroll
      for (int j = 0; j < 4; ++j)
        acc2[i][j] = __builtin_amdgcn_mfma_f32_16x16x32_bf16(af[i], w3[j],
                                                             acc2[i][j], 0, 0, 0);
  }

  // ---- epilogue2: bias + relu -> fp32 out ----
#pragma unroll
  for (int j = 0; j < 4; ++j) {
    int col = wave * 64 + j * 16 + m;
    float bv = b2[col];
#pragma unroll
    for (int i = 0; i < 4; ++i)
#pragma unroll
      for (int r = 0; r < 4; ++r) {
        int row = i * 16 + q * 4 + r;
        float v = acc2[i][j][r] + bv;
        v = v > 0.0f ? v : 0.0f;
        out[(size_t)(row0 + row) * DOUT_ + col] = v;
      }
  }
}

// ---------------- workspace layout ----------------

constexpr size_t OFF_W1S = 0;                    // 256*384*2 = 196608
constexpr size_t OFF_W2S = OFF_W1S + 196608;     // 256*256*2 = 131072
constexpr size_t OFF_IDX = OFF_W2S + 131072;     // 65536*3*4 = 786432
constexpr size_t OFF_W = OFF_IDX + 786432;       // 65536*3*4 = 786432
constexpr size_t WS_TOTAL = OFF_W + 786432;      // ~1.9 MB

extern "C" void kernel_launch(void* const* d_in, const int* in_sizes, int n_in,
                              void* d_out, int out_size, void* d_ws, size_t ws_size,
                              hipStream_t stream) {
  const float* xyz1 = (const float*)d_in[0];
  const float* feat1 = (const float*)d_in[1];
  const float* xyz2 = (const float*)d_in[2];
  const float* feat2 = (const float*)d_in[3];
  const float* W1 = (const float*)d_in[4];
  const float* b1 = (const float*)d_in[5];
  const float* W2 = (const float*)d_in[6];
  const float* b2 = (const float*)d_in[7];

  if (ws_size < WS_TOTAL) return;

  char* ws = (char*)d_ws;
  ushort_t* W1s = (ushort_t*)(ws + OFF_W1S);
  ushort_t* W2s = (ushort_t*)(ws + OFF_W2S);
  int* idx = (int*)(ws + OFF_IDX);
  float* w = (float*)(ws + OFF_W);

  prep_kernel<<<384, 256, 0, stream>>>(W1, W2, W1s, W2s);
  knn_kernel<<<B_ * (N1_ / 64), 128, 0, stream>>>(xyz1, xyz2, idx, w);
  fused_kernel<<<M_ / 64, 256, 0, stream>>>(feat1, feat2, idx, w, W1s, b1, W2s,
                                            b2, (float*)d_out);
}

// Round 6
// 196.386 us; speedup vs baseline: 1.1080x; 1.1080x over previous
//
#include <hip/hip_runtime.h>
#include <cstdint>
#include <cstddef>

typedef unsigned short ushort_t;
typedef unsigned int uint_t;

typedef __bf16 bf16x8 __attribute__((ext_vector_type(8)));
typedef float floatx4 __attribute__((ext_vector_type(4)));

#define B_ 16
#define N1_ 4096
#define N2_ 1024
#define C1_ 128
#define C2_ 256
#define DIN_ 384
#define DOUT_ 256
#define M_ (B_ * N1_)  // 65536

// ---------------- helpers ----------------

__device__ __forceinline__ ushort_t f2bf(float f) {
  unsigned int u = __builtin_bit_cast(unsigned int, f);
  u = (u + 0x7fffu + ((u >> 16) & 1u)) >> 16;  // RNE
  return (ushort_t)u;
}

// As chunk swizzle: XOR the 16B-chunk bits (3-4 of the ushort kk index) with
// (row>>1)&3. Writer granules (8B interp / 4B feat1) stay inside one chunk;
// reader's b128 reads one whole permuted chunk.
#define AS_IDX(t, row, kk) \
  ((t) * 2048 + (row) * 32 + ((kk) ^ ((((row) >> 1) & 3) << 3)))

// ---------------- kernel P: weight swizzle + bf16 convert ----------------
// W1s[t][n][kk] = bf16(W1[t*32+kk][n]), t=0..11, n=0..255, kk=0..31

__global__ __launch_bounds__(256) void prep_kernel(
    const float* __restrict__ W1, const float* __restrict__ W2,
    ushort_t* __restrict__ W1s, ushort_t* __restrict__ W2s) {
  int e = blockIdx.x * 256 + threadIdx.x;
  if (e < DOUT_ * DIN_) {  // 98304
    int kk = e & 31, n = (e >> 5) & 255, t = e >> 13;
    W1s[e] = f2bf(W1[(size_t)(t * 32 + kk) * DOUT_ + n]);
  }
  if (e < DOUT_ * DOUT_) {  // 65536
    int kk = e & 31, n = (e >> 5) & 255, t = e >> 13;
    W2s[e] = f2bf(W2[(size_t)(t * 32 + kk) * DOUT_ + n]);
  }
}

// ---------------- kernel A: 3-NN + inverse-distance weights ----------------
// Structure: 2048 blocks x 256 threads (the full-occupancy 8-waves/SIMD
// config), 1 row/thread, 8 subs/row — BUT each thread runs TWO interleaved
// candidate chains (A: p = sub mod 16, B: p = sub+8 mod 16), folded at the
// end with the index-tiebreak merge. ILP 2 at unchanged TLP.
// Round-5 lesson: ILP4 at 2 waves/SIMD (grid-limited) = 65 us; TLP wins.

__device__ __forceinline__ void ins_exact(float& s0, float& s1, float& s2,
                                          int& i0, int& i1, int& i2,
                                          float d, int p) {
  float ns2 = __builtin_amdgcn_fmed3f(d, s1, s2);
  float ns1 = __builtin_amdgcn_fmed3f(d, s0, s1);
  float ns0 = fminf(d, s0);
  bool c0 = d < s0, c1 = d < s1, c2 = d < s2;
  i2 = c1 ? i1 : (c2 ? p : i2);
  i1 = c0 ? i0 : (c1 ? p : i1);
  i0 = c0 ? p : i0;
  s0 = ns0; s1 = ns1; s2 = ns2;
}

__device__ __forceinline__ void ins_merge(float& s0, float& s1, float& s2,
                                          int& i0, int& i1, int& i2,
                                          float e, int j) {
  bool t0 = (e < s0) || (e == s0 && j < i0);
  bool t1 = (e < s1) || (e == s1 && j < i1);
  bool t2 = (e < s2) || (e == s2 && j < i2);
  s2 = t1 ? s1 : (t2 ? e : s2);
  i2 = t1 ? i1 : (t2 ? j : i2);
  s1 = t0 ? s0 : (t1 ? e : s1);
  i1 = t0 ? i0 : (t1 ? j : i1);
  s0 = t0 ? e : s0;
  i0 = t0 ? j : i0;
}

__global__ __launch_bounds__(256) void knn_kernel(
    const float* __restrict__ xyz1, const float* __restrict__ xyz2,
    int* __restrict__ idx_out, float* __restrict__ w_out) {
  __shared__ float4 xs4[N2_];  // 16 KB
  int b = blockIdx.x >> 7;
  int n1base = (blockIdx.x & 127) << 5;  // 32 rows/block
  const float* p2 = xyz2 + (size_t)b * N2_ * 3;
  for (int i = threadIdx.x; i < N2_; i += 256) {
    const float* s = p2 + 3 * i;
    xs4[i] = make_float4(s[0], s[1], s[2], 0.0f);
  }
  __syncthreads();

  int g = threadIdx.x >> 3;
  int sub = threadIdx.x & 7;
  int row = b * N1_ + n1base + g;
  const float* p1 = xyz1 + (size_t)row * 3;
  float x1 = p1[0], y1 = p1[1], z1 = p1[2];

  float as0 = 3.0e38f, as1 = 3.0e38f, as2 = 3.0e38f;
  float bs0 = 3.0e38f, bs1 = 3.0e38f, bs2 = 3.0e38f;
  int ai0 = 0, ai1 = 0, ai2 = 0;
  int bi0 = 0, bi1 = 0, bi2 = 0;

  int pA = sub;
  int pB = sub + 8;
#pragma unroll 8
  for (int t = 0; t < N2_ / 16; ++t) {
    float4 qa = xs4[pA];
    float4 qb = xs4[pB];
    {
      float dx = x1 - qa.x, dy = y1 - qa.y, dz = y1 == y1 ? z1 - qa.z : 0.0f;
      // (the ?: is a no-op guard the compiler folds; keeps dz defined)
      float d = dx * dx + dy * dy + dz * dz;
      ins_exact(as0, as1, as2, ai0, ai1, ai2, d, pA);
    }
    {
      float dx = x1 - qb.x, dy = y1 - qb.y, dz = z1 - qb.z;
      float d = dx * dx + dy * dy + dz * dz;
      ins_exact(bs0, bs1, bs2, bi0, bi1, bi2, d, pB);
    }
    pA += 16;
    pB += 16;
  }

  // fold chain B into chain A (index-tiebreak; scan-order independent)
  ins_merge(as0, as1, as2, ai0, ai1, ai2, bs0, bi0);
  ins_merge(as0, as1, as2, ai0, ai1, ai2, bs1, bi1);
  ins_merge(as0, as1, as2, ai0, ai1, ai2, bs2, bi2);

#pragma unroll
  for (int mm = 1; mm <= 4; mm <<= 1) {
    float e0 = __shfl_xor(as0, mm), e1 = __shfl_xor(as1, mm), e2 = __shfl_xor(as2, mm);
    int j0 = __shfl_xor(ai0, mm), j1 = __shfl_xor(ai1, mm), j2 = __shfl_xor(ai2, mm);
    ins_merge(as0, as1, as2, ai0, ai1, ai2, e0, j0);
    ins_merge(as0, as1, as2, ai0, ai1, ai2, e1, j1);
    ins_merge(as0, as1, as2, ai0, ai1, ai2, e2, j2);
  }

  if (sub == 0) {
    float r0 = 1.0f / fmaxf(as0, 1e-10f);
    float r1 = 1.0f / fmaxf(as1, 1e-10f);
    float r2 = 1.0f / fmaxf(as2, 1e-10f);
    float s = 1.0f / (r0 + r1 + r2);
    int base = row * 3;
    idx_out[base + 0] = ai0;
    idx_out[base + 1] = ai1;
    idx_out[base + 2] = ai2;
    w_out[base + 0] = r0 * s;
    w_out[base + 1] = r1 * s;
    w_out[base + 2] = r2 * s;
  }
}

// ---------------- fused: build + GEMM1 + GEMM2 ----------------
// (round-5 version, unchanged: As chunk-XOR swizzle + quad-buffered W
// prefetch on the verified 48 KB / 61 us structure)

__global__ __launch_bounds__(256, 2) void fused_kernel(
    const float* __restrict__ feat1, const float* __restrict__ feat2,
    const int* __restrict__ idx, const float* __restrict__ w,
    const ushort_t* __restrict__ W1s, const float* __restrict__ b1,
    const ushort_t* __restrict__ W2s, const float* __restrict__ b2,
    float* __restrict__ out) {
  __shared__ ushort_t As[64 * 384];  // 48 KB; HS (64x256 = 32 KB) aliases front
  const int tid = threadIdx.x;
  const int wave = tid >> 6;
  const int lane = tid & 63;
  const int m = lane & 15;
  const int q = lane >> 4;
  const int row0 = blockIdx.x * 64;
  const int b = row0 >> 12;

  const int b_off = (wave * 64 + m) * 32 + q * 8;  // frag base in W1s/W2s tile

  // W quad-buffers (shared between GEMM1 and GEMM2 phases)
  bf16x8 w0[4], w1[4], w2[4], w3[4], af[4];

  // issue W1 t=0,1 frags now; they complete under the build phase
#pragma unroll
  for (int j = 0; j < 4; ++j) {
    w0[j] = *(const bf16x8*)(W1s + b_off + j * 512);
    w1[j] = *(const bf16x8*)(W1s + 8192 + b_off + j * 512);
  }

  // ---- build phase: As[t][row][kk-swz] (t = k/32), bf16 ----
#pragma unroll 4
  for (int it = 0; it < 16; ++it) {
    int rl = wave * 16 + it;
    int row = row0 + rl;
    const int* ip = idx + (size_t)row * 3;
    const float* wp = w + (size_t)row * 3;
    int i0 = ip[0], i1 = ip[1], i2 = ip[2];
    float w0v = wp[0], w1v = wp[1], w2v = wp[2];

    const float4* f0 = (const float4*)(feat2 + ((size_t)b * N2_ + i0) * C2_);
    const float4* f1 = (const float4*)(feat2 + ((size_t)b * N2_ + i1) * C2_);
    const float4* f2 = (const float4*)(feat2 + ((size_t)b * N2_ + i2) * C2_);
    float4 a = f0[lane];
    float4 c = f1[lane];
    float4 d = f2[lane];
    float vx = w0v * a.x + w1v * c.x + w2v * d.x;
    float vy = w0v * a.y + w1v * c.y + w2v * d.y;
    float vz = w0v * a.z + w1v * c.z + w2v * d.z;
    float vw = w0v * a.w + w1v * c.w + w2v * d.w;
    // cols 4*lane .. 4*lane+3 (8B granule, stays inside one 16B chunk)
    uint_t lo = (uint_t)f2bf(vx) | ((uint_t)f2bf(vy) << 16);
    uint_t hi = (uint_t)f2bf(vz) | ((uint_t)f2bf(vw) << 16);
    int e = AS_IDX(lane >> 3, rl, (4 * lane) & 31);
    *(uint2*)&As[e] = make_uint2(lo, hi);

    // feat1: cols 256 + 2*lane, 2*lane+1 (4B granule)
    float2 t1 = ((const float2*)(feat1 + (size_t)row * C1_))[lane];
    uint_t pk = (uint_t)f2bf(t1.x) | ((uint_t)f2bf(t1.y) << 16);
    int e1 = AS_IDX(8 + (lane >> 4), rl, (2 * lane) & 31);
    *(uint_t*)&As[e1] = pk;
  }
  __syncthreads();

  // ---- GEMM1: K = 384 (12 t-steps), quad-buffered W prefetch ----
  floatx4 acc[4][4];
#pragma unroll
  for (int i = 0; i < 4; ++i)
#pragma unroll
    for (int j = 0; j < 4; ++j) acc[i][j] = (floatx4)0.0f;

#pragma unroll
  for (int tt = 0; tt < 12; tt += 4) {
#pragma unroll
    for (int j = 0; j < 4; ++j) {
      w2[j] = *(const bf16x8*)(W1s + (size_t)(tt + 2) * 8192 + b_off + j * 512);
      w3[j] = *(const bf16x8*)(W1s + (size_t)(tt + 3) * 8192 + b_off + j * 512);
    }
#pragma unroll
    for (int i = 0; i < 4; ++i)
      af[i] = *(const bf16x8*)&As[AS_IDX(tt, m + 16 * i, q * 8)];
#pragma unroll
    for (int i = 0; i < 4; ++i)
#pragma unroll
      for (int j = 0; j < 4; ++j)
        acc[i][j] = __builtin_amdgcn_mfma_f32_16x16x32_bf16(af[i], w0[j],
                                                            acc[i][j], 0, 0, 0);
#pragma unroll
    for (int i = 0; i < 4; ++i)
      af[i] = *(const bf16x8*)&As[AS_IDX(tt + 1, m + 16 * i, q * 8)];
#pragma unroll
    for (int i = 0; i < 4; ++i)
#pragma unroll
      for (int j = 0; j < 4; ++j)
        acc[i][j] = __builtin_amdgcn_mfma_f32_16x16x32_bf16(af[i], w1[j],
                                                            acc[i][j], 0, 0, 0);
    if (tt + 4 < 12) {
#pragma unroll
      for (int j = 0; j < 4; ++j) {
        w0[j] = *(const bf16x8*)(W1s + (size_t)(tt + 4) * 8192 + b_off + j * 512);
        w1[j] = *(const bf16x8*)(W1s + (size_t)(tt + 5) * 8192 + b_off + j * 512);
      }
    }
#pragma unroll
    for (int i = 0; i < 4; ++i)
      af[i] = *(const bf16x8*)&As[AS_IDX(tt + 2, m + 16 * i, q * 8)];
#pragma unroll
    for (int i = 0; i < 4; ++i)
#pragma unroll
      for (int j = 0; j < 4; ++j)
        acc[i][j] = __builtin_amdgcn_mfma_f32_16x16x32_bf16(af[i], w2[j],
                                                            acc[i][j], 0, 0, 0);
#pragma unroll
    for (int i = 0; i < 4; ++i)
      af[i] = *(const bf16x8*)&As[AS_IDX(tt + 3, m + 16 * i, q * 8)];
#pragma unroll
    for (int i = 0; i < 4; ++i)
#pragma unroll
      for (int j = 0; j < 4; ++j)
        acc[i][j] = __builtin_amdgcn_mfma_f32_16x16x32_bf16(af[i], w3[j],
                                                            acc[i][j], 0, 0, 0);
  }

  // issue W2 t=0,1 frags now; they complete under epilogue1
#pragma unroll
  for (int j = 0; j < 4; ++j) {
    w0[j] = *(const bf16x8*)(W2s + b_off + j * 512);
    w1[j] = *(const bf16x8*)(W2s + 8192 + b_off + j * 512);
  }
  __syncthreads();  // all As reads done before HS overwrites the region

  // ---- epilogue1: bias + relu -> bf16 HS (aliases As; XOR-chunk swizzle) ----
  ushort_t* HS = As;  // 64 x 256 = 16384 elems
#pragma unroll
  for (int j = 0; j < 4; ++j) {
    int col = wave * 64 + j * 16 + m;
    float bv = b1[col];
    int cb = (col >> 3) & 3;
    int tb = (col >> 5) * 2048 + (col & 7);
#pragma unroll
    for (int i = 0; i < 4; ++i)
#pragma unroll
      for (int r = 0; r < 4; ++r) {
        int row = i * 16 + q * 4 + r;
        float v = acc[i][j][r] + bv;
        v = v > 0.0f ? v : 0.0f;
        int ch = cb ^ ((row >> 2) & 3);
        HS[tb + row * 32 + ch * 8] = f2bf(v);
      }
  }
  __syncthreads();

  // ---- GEMM2: K = 256 (8 t-steps), a-frags from HS, quad-buffered W ----
  floatx4 acc2[4][4];
#pragma unroll
  for (int i = 0; i < 4; ++i)
#pragma unroll
    for (int j = 0; j < 4; ++j) acc2[i][j] = (floatx4)0.0f;

#pragma unroll
  for (int tt = 0; tt < 8; tt += 4) {
#pragma unroll
    for (int j = 0; j < 4; ++j) {
      w2[j] = *(const bf16x8*)(W2s + (size_t)(tt + 2) * 8192 + b_off + j * 512);
      w3[j] = *(const bf16x8*)(W2s + (size_t)(tt + 3) * 8192 + b_off + j * 512);
    }
#pragma unroll
    for (int i = 0; i < 4; ++i) {
      int row = m + 16 * i;
      int ch = q ^ ((row >> 2) & 3);
      af[i] = *(const bf16x8*)&HS[tt * 2048 + row * 32 + ch * 8];
    }
#pragma unroll
    for (int i = 0; i < 4; ++i)
#pragma unroll
      for (int j = 0; j < 4; ++j)
        acc2[i][j] = __builtin_amdgcn_mfma_f32_16x16x32_bf16(af[i], w0[j],
                                                             acc2[i][j], 0, 0, 0);
#pragma unroll
    for (int i = 0; i < 4; ++i) {
      int row = m + 16 * i;
      int ch = q ^ ((row >> 2) & 3);
      af[i] = *(const bf16x8*)&HS[(tt + 1) * 2048 + row * 32 + ch * 8];
    }
#pragma unroll
    for (int i = 0; i < 4; ++i)
#pragma unroll
      for (int j = 0; j < 4; ++j)
        acc2[i][j] = __builtin_amdgcn_mfma_f32_16x16x32_bf16(af[i], w1[j],
                                                             acc2[i][j], 0, 0, 0);
    if (tt + 4 < 8) {
#pragma unroll
      for (int j = 0; j < 4; ++j) {
        w0[j] = *(const bf16x8*)(W2s + (size_t)(tt + 4) * 8192 + b_off + j * 512);
        w1[j] = *(const bf16x8*)(W2s + (size_t)(tt + 5) * 8192 + b_off + j * 512);
      }
    }
#pragma unroll
    for (int i = 0; i < 4; ++i) {
      int row = m + 16 * i;
      int ch = q ^ ((row >> 2) & 3);
      af[i] = *(const bf16x8*)&HS[(tt + 2) * 2048 + row * 32 + ch * 8];
    }
#pragma unroll
    for (int i = 0; i < 4; ++i)
#pragma unroll
      for (int j = 0; j < 4; ++j)
        acc2[i][j] = __builtin_amdgcn_mfma_f32_16x16x32_bf16(af[i], w2[j],
                                                             acc2[i][j], 0, 0, 0);
#pragma unroll
    for (int i = 0; i < 4; ++i) {
      int row = m + 16 * i;
      int ch = q ^ ((row >> 2) & 3);
      af[i] = *(const bf16x8*)&HS[(tt + 3) * 2048 + row * 32 + ch * 8];
    }
#pragma unroll
    for (int i = 0; i < 4; ++i)
#pragma unroll
      for (int j = 0; j < 4; ++j)
        acc2[i][j] = __builtin_amdgcn_mfma_f32_16x16x32_bf16(af[i], w3[j],
                                                             acc2[i][j], 0, 0, 0);
  }

  // ---- epilogue2: bias + relu -> fp32 out ----
#pragma unroll
  for (int j = 0; j < 4; ++j) {
    int col = wave * 64 + j * 16 + m;
    float bv = b2[col];
#pragma unroll
    for (int i = 0; i < 4; ++i)
#pragma unroll
      for (int r = 0; r < 4; ++r) {
        int row = i * 16 + q * 4 + r;
        float v = acc2[i][j][r] + bv;
        v = v > 0.0f ? v : 0.0f;
        out[(size_t)(row0 + row) * DOUT_ + col] = v;
      }
  }
}

// ---------------- workspace layout ----------------

constexpr size_t OFF_W1S = 0;                    // 256*384*2 = 196608
constexpr size_t OFF_W2S = OFF_W1S + 196608;     // 256*256*2 = 131072
constexpr size_t OFF_IDX = OFF_W2S + 131072;     // 65536*3*4 = 786432
constexpr size_t OFF_W = OFF_IDX + 786432;       // 65536*3*4 = 786432
constexpr size_t WS_TOTAL = OFF_W + 786432;      // ~1.9 MB

extern "C" void kernel_launch(void* const* d_in, const int* in_sizes, int n_in,
                              void* d_out, int out_size, void* d_ws, size_t ws_size,
                              hipStream_t stream) {
  const float* xyz1 = (const float*)d_in[0];
  const float* feat1 = (const float*)d_in[1];
  const float* xyz2 = (const float*)d_in[2];
  const float* feat2 = (const float*)d_in[3];
  const float* W1 = (const float*)d_in[4];
  const float* b1 = (const float*)d_in[5];
  const float* W2 = (const float*)d_in[6];
  const float* b2 = (const float*)d_in[7];

  if (ws_size < WS_TOTAL) return;

  char* ws = (char*)d_ws;
  ushort_t* W1s = (ushort_t*)(ws + OFF_W1S);
  ushort_t* W2s = (ushort_t*)(ws + OFF_W2S);
  int* idx = (int*)(ws + OFF_IDX);
  float* w = (float*)(ws + OFF_W);

  prep_kernel<<<384, 256, 0, stream>>>(W1, W2, W1s, W2s);
  knn_kernel<<<B_ * (N1_ / 32), 256, 0, stream>>>(xyz1, xyz2, idx, w);
  fused_kernel<<<M_ / 64, 256, 0, stream>>>(feat1, feat2, idx, w, W1s, b1, W2s,
                                            b2, (float*)d_out);
}

// Round 7
// 192.931 us; speedup vs baseline: 1.1278x; 1.0179x over previous
//
#include <hip/hip_runtime.h>
#include <cstdint>
#include <cstddef>

typedef unsigned short ushort_t;
typedef unsigned int uint_t;

typedef __bf16 bf16x8 __attribute__((ext_vector_type(8)));
typedef float floatx4 __attribute__((ext_vector_type(4)));

#define B_ 16
#define N1_ 4096
#define N2_ 1024
#define C1_ 128
#define C2_ 256
#define DIN_ 384
#define DOUT_ 256
#define M_ (B_ * N1_)  // 65536

// ---------------- helpers ----------------

__device__ __forceinline__ ushort_t f2bf(float f) {
  unsigned int u = __builtin_bit_cast(unsigned int, f);
  u = (u + 0x7fffu + ((u >> 16) & 1u)) >> 16;  // RNE
  return (ushort_t)u;
}

// ---------------- kernel P: weight swizzle + bf16 convert ----------------
// W1s[t][n][kk] = bf16(W1[t*32+kk][n]), t=0..11, n=0..255, kk=0..31

__global__ __launch_bounds__(256) void prep_kernel(
    const float* __restrict__ W1, const float* __restrict__ W2,
    ushort_t* __restrict__ W1s, ushort_t* __restrict__ W2s) {
  int e = blockIdx.x * 256 + threadIdx.x;
  if (e < DOUT_ * DIN_) {  // 98304
    int kk = e & 31, n = (e >> 5) & 255, t = e >> 13;
    W1s[e] = f2bf(W1[(size_t)(t * 32 + kk) * DOUT_ + n]);
  }
  if (e < DOUT_ * DOUT_) {  // 65536
    int kk = e & 31, n = (e >> 5) & 255, t = e >> 13;
    W2s[e] = f2bf(W2[(size_t)(t * 32 + kk) * DOUT_ + n]);
  }
}

// ---------------- knn primitives (verbatim from verified kernel) ----------

__device__ __forceinline__ void ins_exact(float& s0, float& s1, float& s2,
                                          int& i0, int& i1, int& i2,
                                          float d, int p) {
  float ns2 = __builtin_amdgcn_fmed3f(d, s1, s2);
  float ns1 = __builtin_amdgcn_fmed3f(d, s0, s1);
  float ns0 = fminf(d, s0);
  bool c0 = d < s0, c1 = d < s1, c2 = d < s2;
  i2 = c1 ? i1 : (c2 ? p : i2);
  i1 = c0 ? i0 : (c1 ? p : i1);
  i0 = c0 ? p : i0;
  s0 = ns0; s1 = ns1; s2 = ns2;
}

__device__ __forceinline__ void ins_merge(float& s0, float& s1, float& s2,
                                          int& i0, int& i1, int& i2,
                                          float e, int j) {
  bool t0 = (e < s0) || (e == s0 && j < i0);
  bool t1 = (e < s1) || (e == s1 && j < i1);
  bool t2 = (e < s2) || (e == s2 && j < i2);
  s2 = t1 ? s1 : (t2 ? e : s2);
  i2 = t1 ? i1 : (t2 ? j : i2);
  s1 = t0 ? s0 : (t1 ? e : s1);
  i1 = t0 ? i0 : (t1 ? j : i1);
  s0 = t0 ? e : s0;
  i0 = t0 ? j : i0;
}

// ---------------- fully fused: knn + build + GEMM1 + GEMM2 ----------------
// 64 rows/block, 1024 blocks, 256 threads (4 waves; wave w owns col-quarter
// [64w,64w+64) of both GEMMs). The knn phase (rows g, g+32 per thread, 8
// subs/row, scan order p = sub + 8t — semantics byte-identical to the
// verified standalone kernel) runs as a prologue using the As LDS region for
// xs4 (16 KB, dead before build overwrites it); results go to 1.5 KB
// idxL/wL. Build/GEMM1/epi1/GEMM2/epi2 are VERBATIM the harness-verified
// 61 us body (48 KB As incl. feat1, dual-buffered W frags, no swizzle —
// round-6 showed the swizzle/quad-buffer variants are neutral-to-negative).
// Win mechanism: block-level phase skew -> knn (VALU/LDS pipes) of one
// resident block overlaps build-gather/MFMA of others; the 44 us serial knn
// dispatch and its idx/w global round-trip disappear.

__global__ __launch_bounds__(256, 2) void fused_kernel(
    const float* __restrict__ xyz1, const float* __restrict__ xyz2,
    const float* __restrict__ feat1, const float* __restrict__ feat2,
    const ushort_t* __restrict__ W1s, const float* __restrict__ b1,
    const ushort_t* __restrict__ W2s, const float* __restrict__ b2,
    float* __restrict__ out) {
  __shared__ __align__(16) ushort_t As[64 * 384];  // 48 KB; xs4+HS alias it
  __shared__ int idxL[64 * 3];
  __shared__ float wL[64 * 3];

  const int tid = threadIdx.x;
  const int wave = tid >> 6;
  const int lane = tid & 63;
  const int m = lane & 15;
  const int q = lane >> 4;
  const int row0 = blockIdx.x * 64;
  const int b = row0 >> 12;

  // ---- stage xyz2 batch slice into LDS (aliases As front 16 KB) ----
  float4* xs4 = (float4*)As;
  {
    const float4* p24 = (const float4*)(xyz2 + (size_t)b * (N2_ * 3));
    float4 A = p24[3 * tid + 0];
    float4 Bv = p24[3 * tid + 1];
    float4 Cv = p24[3 * tid + 2];
    xs4[4 * tid + 0] = make_float4(A.x, A.y, A.z, 0.0f);
    xs4[4 * tid + 1] = make_float4(A.w, Bv.x, Bv.y, 0.0f);
    xs4[4 * tid + 2] = make_float4(Bv.z, Bv.w, Cv.x, 0.0f);
    xs4[4 * tid + 3] = make_float4(Cv.y, Cv.z, Cv.w, 0.0f);
  }
  __syncthreads();

  // ---- knn: 2 rows/thread (one xs4 read feeds both), 8 subs/row ----
  {
    const int g = tid >> 3;  // row pair {g, g+32}
    const int sub = tid & 7;
    const float* pa = xyz1 + (size_t)(row0 + g) * 3;
    const float* pb = xyz1 + (size_t)(row0 + g + 32) * 3;
    float ax = pa[0], ay = pa[1], az = pa[2];
    float bx = pb[0], by = pb[1], bz = pb[2];
    float as0 = 3.0e38f, as1 = 3.0e38f, as2 = 3.0e38f;
    float bs0 = 3.0e38f, bs1 = 3.0e38f, bs2 = 3.0e38f;
    int ai0 = 0, ai1 = 0, ai2 = 0, bi0 = 0, bi1 = 0, bi2 = 0;
    int p = sub;
#pragma unroll 4
    for (int t = 0; t < N2_ / 8; ++t) {
      float4 qv = xs4[p];
      {
        float dx = ax - qv.x, dy = ay - qv.y, dz = az - qv.z;
        float d = dx * dx + dy * dy + dz * dz;
        ins_exact(as0, as1, as2, ai0, ai1, ai2, d, p);
      }
      {
        float dx = bx - qv.x, dy = by - qv.y, dz = bz - qv.z;
        float d = dx * dx + dy * dy + dz * dz;
        ins_exact(bs0, bs1, bs2, bi0, bi1, bi2, d, p);
      }
      p += 8;
    }
#pragma unroll
    for (int mm = 1; mm <= 4; mm <<= 1) {
      {
        float e0 = __shfl_xor(as0, mm), e1 = __shfl_xor(as1, mm), e2 = __shfl_xor(as2, mm);
        int j0 = __shfl_xor(ai0, mm), j1 = __shfl_xor(ai1, mm), j2 = __shfl_xor(ai2, mm);
        ins_merge(as0, as1, as2, ai0, ai1, ai2, e0, j0);
        ins_merge(as0, as1, as2, ai0, ai1, ai2, e1, j1);
        ins_merge(as0, as1, as2, ai0, ai1, ai2, e2, j2);
      }
      {
        float e0 = __shfl_xor(bs0, mm), e1 = __shfl_xor(bs1, mm), e2 = __shfl_xor(bs2, mm);
        int j0 = __shfl_xor(bi0, mm), j1 = __shfl_xor(bi1, mm), j2 = __shfl_xor(bi2, mm);
        ins_merge(bs0, bs1, bs2, bi0, bi1, bi2, e0, j0);
        ins_merge(bs0, bs1, bs2, bi0, bi1, bi2, e1, j1);
        ins_merge(bs0, bs1, bs2, bi0, bi1, bi2, e2, j2);
      }
    }
    if (sub == 0) {
      float r0 = 1.0f / fmaxf(as0, 1e-10f);
      float r1 = 1.0f / fmaxf(as1, 1e-10f);
      float r2 = 1.0f / fmaxf(as2, 1e-10f);
      float s = 1.0f / (r0 + r1 + r2);
      idxL[g * 3 + 0] = ai0; idxL[g * 3 + 1] = ai1; idxL[g * 3 + 2] = ai2;
      wL[g * 3 + 0] = r0 * s; wL[g * 3 + 1] = r1 * s; wL[g * 3 + 2] = r2 * s;
      r0 = 1.0f / fmaxf(bs0, 1e-10f);
      r1 = 1.0f / fmaxf(bs1, 1e-10f);
      r2 = 1.0f / fmaxf(bs2, 1e-10f);
      s = 1.0f / (r0 + r1 + r2);
      idxL[(g + 32) * 3 + 0] = bi0; idxL[(g + 32) * 3 + 1] = bi1; idxL[(g + 32) * 3 + 2] = bi2;
      wL[(g + 32) * 3 + 0] = r0 * s; wL[(g + 32) * 3 + 1] = r1 * s; wL[(g + 32) * 3 + 2] = r2 * s;
    }
  }
  __syncthreads();  // all xs4 reads done before build overwrites As

  // ---- build phase: As[t][row][kk] (t = k/32), bf16 (verbatim R0) ----
#pragma unroll 4
  for (int it = 0; it < 16; ++it) {
    int rl = wave * 16 + it;
    int row = row0 + rl;
    int i0 = idxL[rl * 3 + 0], i1 = idxL[rl * 3 + 1], i2 = idxL[rl * 3 + 2];
    float w0 = wL[rl * 3 + 0], w1 = wL[rl * 3 + 1], w2 = wL[rl * 3 + 2];

    const float4* f0 = (const float4*)(feat2 + ((size_t)b * N2_ + i0) * C2_);
    const float4* f1 = (const float4*)(feat2 + ((size_t)b * N2_ + i1) * C2_);
    const float4* f2 = (const float4*)(feat2 + ((size_t)b * N2_ + i2) * C2_);
    float4 a = f0[lane];
    float4 c = f1[lane];
    float4 d = f2[lane];
    float vx = w0 * a.x + w1 * c.x + w2 * d.x;
    float vy = w0 * a.y + w1 * c.y + w2 * d.y;
    float vz = w0 * a.z + w1 * c.z + w2 * d.z;
    float vw = w0 * a.w + w1 * c.w + w2 * d.w;
    // cols 4*lane .. 4*lane+3 (never straddle a 32-col tile)
    uint_t lo = (uint_t)f2bf(vx) | ((uint_t)f2bf(vy) << 16);
    uint_t hi = (uint_t)f2bf(vz) | ((uint_t)f2bf(vw) << 16);
    int e = (lane >> 3) * 2048 + rl * 32 + ((4 * lane) & 31);
    *(uint2*)&As[e] = make_uint2(lo, hi);

    // feat1: cols 256 + 2*lane, 2*lane+1
    float2 t1 = ((const float2*)(feat1 + (size_t)row * C1_))[lane];
    uint_t pk = (uint_t)f2bf(t1.x) | ((uint_t)f2bf(t1.y) << 16);
    int e1 = (8 + (lane >> 4)) * 2048 + rl * 32 + ((2 * lane) & 31);
    *(uint_t*)&As[e1] = pk;
  }
  __syncthreads();

  // ---- GEMM1: acc[64 rows][64 cols per wave], K = 384, no barriers ----
  const int b_off = (wave * 64 + m) * 32 + q * 8;  // frag base in W1s/W2s tile
  const int a_base = m * 32 + q * 8;

  floatx4 acc[4][4];
#pragma unroll
  for (int i = 0; i < 4; ++i)
#pragma unroll
    for (int j = 0; j < 4; ++j) acc[i][j] = (floatx4)0.0f;

  {
    bf16x8 bf0[4], bf1[4], af[4];
#pragma unroll
    for (int j = 0; j < 4; ++j)
      bf0[j] = *(const bf16x8*)(W1s + b_off + j * 512);
#pragma unroll
    for (int t = 0; t < 12; t += 2) {
#pragma unroll
      for (int j = 0; j < 4; ++j)
        bf1[j] = *(const bf16x8*)(W1s + (size_t)(t + 1) * 8192 + b_off + j * 512);
#pragma unroll
      for (int i = 0; i < 4; ++i)
        af[i] = *(const bf16x8*)&As[t * 2048 + a_base + i * 512];
#pragma unroll
      for (int i = 0; i < 4; ++i)
#pragma unroll
        for (int j = 0; j < 4; ++j)
          acc[i][j] = __builtin_amdgcn_mfma_f32_16x16x32_bf16(af[i], bf0[j],
                                                              acc[i][j], 0, 0, 0);
      if (t + 2 < 12) {
#pragma unroll
        for (int j = 0; j < 4; ++j)
          bf0[j] = *(const bf16x8*)(W1s + (size_t)(t + 2) * 8192 + b_off + j * 512);
      }
#pragma unroll
      for (int i = 0; i < 4; ++i)
        af[i] = *(const bf16x8*)&As[(t + 1) * 2048 + a_base + i * 512];
#pragma unroll
      for (int i = 0; i < 4; ++i)
#pragma unroll
        for (int j = 0; j < 4; ++j)
          acc[i][j] = __builtin_amdgcn_mfma_f32_16x16x32_bf16(af[i], bf1[j],
                                                              acc[i][j], 0, 0, 0);
    }
  }
  __syncthreads();  // all As reads done before HS overwrites the region

  // ---- epilogue1: bias + relu -> bf16 HS (aliases As; XOR-chunk swizzle) ----
  ushort_t* HS = As;  // 64 x 256 = 16384 elems
#pragma unroll
  for (int j = 0; j < 4; ++j) {
    int col = wave * 64 + j * 16 + m;
    float bv = b1[col];
    int cb = (col >> 3) & 3;
    int tb = (col >> 5) * 2048 + (col & 7);
#pragma unroll
    for (int i = 0; i < 4; ++i)
#pragma unroll
      for (int r = 0; r < 4; ++r) {
        int row = i * 16 + q * 4 + r;
        float v = acc[i][j][r] + bv;
        v = v > 0.0f ? v : 0.0f;
        int ch = cb ^ ((row >> 2) & 3);
        HS[tb + row * 32 + ch * 8] = f2bf(v);
      }
  }
  __syncthreads();

  // ---- GEMM2: K = 256, a-frags from HS, no barriers ----
  floatx4 acc2[4][4];
#pragma unroll
  for (int i = 0; i < 4; ++i)
#pragma unroll
    for (int j = 0; j < 4; ++j) acc2[i][j] = (floatx4)0.0f;

  {
    bf16x8 bf0[4], bf1[4], af[4];
#pragma unroll
    for (int j = 0; j < 4; ++j)
      bf0[j] = *(const bf16x8*)(W2s + b_off + j * 512);
#pragma unroll
    for (int t = 0; t < 8; t += 2) {
#pragma unroll
      for (int j = 0; j < 4; ++j)
        bf1[j] = *(const bf16x8*)(W2s + (size_t)(t + 1) * 8192 + b_off + j * 512);
#pragma unroll
      for (int i = 0; i < 4; ++i) {
        int row = m + 16 * i;
        int ch = q ^ ((row >> 2) & 3);
        af[i] = *(const bf16x8*)&HS[t * 2048 + row * 32 + ch * 8];
      }
#pragma unroll
      for (int i = 0; i < 4; ++i)
#pragma unroll
        for (int j = 0; j < 4; ++j)
          acc2[i][j] = __builtin_amdgcn_mfma_f32_16x16x32_bf16(af[i], bf0[j],
                                                               acc2[i][j], 0, 0, 0);
      if (t + 2 < 8) {
#pragma unroll
        for (int j = 0; j < 4; ++j)
          bf0[j] = *(const bf16x8*)(W2s + (size_t)(t + 2) * 8192 + b_off + j * 512);
      }
#pragma unroll
      for (int i = 0; i < 4; ++i) {
        int row = m + 16 * i;
        int ch = q ^ ((row >> 2) & 3);
        af[i] = *(const bf16x8*)&HS[(t + 1) * 2048 + row * 32 + ch * 8];
      }
#pragma unroll
      for (int i = 0; i < 4; ++i)
#pragma unroll
        for (int j = 0; j < 4; ++j)
          acc2[i][j] = __builtin_amdgcn_mfma_f32_16x16x32_bf16(af[i], bf1[j],
                                                               acc2[i][j], 0, 0, 0);
    }
  }

  // ---- epilogue2: bias + relu -> fp32 out ----
#pragma unroll
  for (int j = 0; j < 4; ++j) {
    int col = wave * 64 + j * 16 + m;
    float bv = b2[col];
#pragma unroll
    for (int i = 0; i < 4; ++i)
#pragma unroll
      for (int r = 0; r < 4; ++r) {
        int row = i * 16 + q * 4 + r;
        float v = acc2[i][j][r] + bv;
        v = v > 0.0f ? v : 0.0f;
        out[(size_t)(row0 + row) * DOUT_ + col] = v;
      }
  }
}

// ---------------- workspace layout ----------------

constexpr size_t OFF_W1S = 0;                  // 256*384*2 = 196608
constexpr size_t OFF_W2S = OFF_W1S + 196608;   // 256*256*2 = 131072
constexpr size_t WS_TOTAL = OFF_W2S + 131072;  // 320 KB

extern "C" void kernel_launch(void* const* d_in, const int* in_sizes, int n_in,
                              void* d_out, int out_size, void* d_ws, size_t ws_size,
                              hipStream_t stream) {
  const float* xyz1 = (const float*)d_in[0];
  const float* feat1 = (const float*)d_in[1];
  const float* xyz2 = (const float*)d_in[2];
  const float* feat2 = (const float*)d_in[3];
  const float* W1 = (const float*)d_in[4];
  const float* b1 = (const float*)d_in[5];
  const float* W2 = (const float*)d_in[6];
  const float* b2 = (const float*)d_in[7];

  if (ws_size < WS_TOTAL) return;

  char* ws = (char*)d_ws;
  ushort_t* W1s = (ushort_t*)(ws + OFF_W1S);
  ushort_t* W2s = (ushort_t*)(ws + OFF_W2S);

  prep_kernel<<<384, 256, 0, stream>>>(W1, W2, W1s, W2s);
  fused_kernel<<<M_ / 64, 256, 0, stream>>>(xyz1, xyz2, feat1, feat2, W1s, b1,
                                            W2s, b2, (float*)d_out);
}

// Round 8
// 182.023 us; speedup vs baseline: 1.1954x; 1.0599x over previous
//
#include <hip/hip_runtime.h>
#include <cstdint>
#include <cstddef>

typedef unsigned short ushort_t;
typedef unsigned int uint_t;

typedef __bf16 bf16x8 __attribute__((ext_vector_type(8)));
typedef float floatx4 __attribute__((ext_vector_type(4)));

#define B_ 16
#define N1_ 4096
#define N2_ 1024
#define C1_ 128
#define C2_ 256
#define DIN_ 384
#define DOUT_ 256
#define M_ (B_ * N1_)  // 65536

// ---------------- helpers ----------------

__device__ __forceinline__ ushort_t f2bf(float f) {
  unsigned int u = __builtin_bit_cast(unsigned int, f);
  u = (u + 0x7fffu + ((u >> 16) & 1u)) >> 16;  // RNE
  return (ushort_t)u;
}

// ---------------- kernel P: weight swizzle + bf16 convert ----------------
// W1s[t][n][kk] = bf16(W1[t*32+kk][n]), t=0..11, n=0..255, kk=0..31

__global__ __launch_bounds__(256) void prep_kernel(
    const float* __restrict__ W1, const float* __restrict__ W2,
    ushort_t* __restrict__ W1s, ushort_t* __restrict__ W2s) {
  int e = blockIdx.x * 256 + threadIdx.x;
  if (e < DOUT_ * DIN_) {  // 98304
    int kk = e & 31, n = (e >> 5) & 255, t = e >> 13;
    W1s[e] = f2bf(W1[(size_t)(t * 32 + kk) * DOUT_ + n]);
  }
  if (e < DOUT_ * DOUT_) {  // 65536
    int kk = e & 31, n = (e >> 5) & 255, t = e >> 13;
    W2s[e] = f2bf(W2[(size_t)(t * 32 + kk) * DOUT_ + n]);
  }
}

// ---------------- knn primitives (verbatim from verified kernel) ----------

__device__ __forceinline__ void ins_exact(float& s0, float& s1, float& s2,
                                          int& i0, int& i1, int& i2,
                                          float d, int p) {
  float ns2 = __builtin_amdgcn_fmed3f(d, s1, s2);
  float ns1 = __builtin_amdgcn_fmed3f(d, s0, s1);
  float ns0 = fminf(d, s0);
  bool c0 = d < s0, c1 = d < s1, c2 = d < s2;
  i2 = c1 ? i1 : (c2 ? p : i2);
  i1 = c0 ? i0 : (c1 ? p : i1);
  i0 = c0 ? p : i0;
  s0 = ns0; s1 = ns1; s2 = ns2;
}

__device__ __forceinline__ void ins_merge(float& s0, float& s1, float& s2,
                                          int& i0, int& i1, int& i2,
                                          float e, int j) {
  bool t0 = (e < s0) || (e == s0 && j < i0);
  bool t1 = (e < s1) || (e == s1 && j < i1);
  bool t2 = (e < s2) || (e == s2 && j < i2);
  s2 = t1 ? s1 : (t2 ? e : s2);
  i2 = t1 ? i1 : (t2 ? j : i2);
  s1 = t0 ? s0 : (t1 ? e : s1);
  i1 = t0 ? i0 : (t1 ? j : i1);
  s0 = t0 ? e : s0;
  i0 = t0 ? j : i0;
}

// ---------------- fully fused: knn + build + GEMM1 + GEMM2 ----------------
// ROUND-8 CHANGE: 32 rows/block (was 64), 2048 blocks. As = 24 KB (+0.75 KB
// idx/w) -> 3-6 blocks/CU instead of 2. R7 showed the mega-fusion runs but
// phases stay serialized because only 2 lockstep blocks co-reside (occupancy
// 22%); smaller blocks give the scheduler 3-6 blocks at independently
// drifting phases so knn (VALU), build (VMEM gather), and GEMM (MFMA)
// cross-hide. knn phase = byte-identical semantics & geometry to the
// verified standalone 44 us kernel (32 rows, 8 subs, 1 chain).

__global__ __launch_bounds__(256, 2) void fused_kernel(
    const float* __restrict__ xyz1, const float* __restrict__ xyz2,
    const float* __restrict__ feat1, const float* __restrict__ feat2,
    const ushort_t* __restrict__ W1s, const float* __restrict__ b1,
    const ushort_t* __restrict__ W2s, const float* __restrict__ b2,
    float* __restrict__ out) {
  __shared__ __align__(16) ushort_t As[32 * 384];  // 24 KB; xs4 (16 KB) + HS (16 KB) alias it
  __shared__ int idxL[32 * 3];
  __shared__ float wL[32 * 3];

  const int tid = threadIdx.x;
  const int wave = tid >> 6;
  const int lane = tid & 63;
  const int m = lane & 15;
  const int q = lane >> 4;
  const int row0 = blockIdx.x * 32;
  const int b = row0 >> 12;

  // ---- stage xyz2 batch slice into LDS (aliases As front 16 KB) ----
  float4* xs4 = (float4*)As;
  {
    const float4* p24 = (const float4*)(xyz2 + (size_t)b * (N2_ * 3));
    float4 A = p24[3 * tid + 0];
    float4 Bv = p24[3 * tid + 1];
    float4 Cv = p24[3 * tid + 2];
    xs4[4 * tid + 0] = make_float4(A.x, A.y, A.z, 0.0f);
    xs4[4 * tid + 1] = make_float4(A.w, Bv.x, Bv.y, 0.0f);
    xs4[4 * tid + 2] = make_float4(Bv.z, Bv.w, Cv.x, 0.0f);
    xs4[4 * tid + 3] = make_float4(Cv.y, Cv.z, Cv.w, 0.0f);
  }
  __syncthreads();

  // ---- knn: verbatim standalone geometry (32 rows, 8 subs/row, 1 chain) ----
  {
    const int g = tid >> 3;  // 0..31
    const int sub = tid & 7;
    const int row = row0 + g;
    const float* p1 = xyz1 + (size_t)row * 3;
    float x1 = p1[0], y1 = p1[1], z1 = p1[2];

    float s0 = 3.0e38f, s1 = 3.0e38f, s2 = 3.0e38f;
    int i0 = 0, i1 = 0, i2 = 0;

    int p = sub;
#pragma unroll 8
    for (int t = 0; t < N2_ / 8; ++t) {
      float4 qv = xs4[p];
      float dx = x1 - qv.x;
      float dy = y1 - qv.y;
      float dz = z1 - qv.z;
      float d = dx * dx + dy * dy + dz * dz;
      ins_exact(s0, s1, s2, i0, i1, i2, d, p);
      p += 8;
    }

#pragma unroll
    for (int mm = 1; mm <= 4; mm <<= 1) {
      float e0 = __shfl_xor(s0, mm), e1 = __shfl_xor(s1, mm), e2 = __shfl_xor(s2, mm);
      int j0 = __shfl_xor(i0, mm), j1 = __shfl_xor(i1, mm), j2 = __shfl_xor(i2, mm);
      ins_merge(s0, s1, s2, i0, i1, i2, e0, j0);
      ins_merge(s0, s1, s2, i0, i1, i2, e1, j1);
      ins_merge(s0, s1, s2, i0, i1, i2, e2, j2);
    }

    if (sub == 0) {
      float r0 = 1.0f / fmaxf(s0, 1e-10f);
      float r1 = 1.0f / fmaxf(s1, 1e-10f);
      float r2 = 1.0f / fmaxf(s2, 1e-10f);
      float s = 1.0f / (r0 + r1 + r2);
      idxL[g * 3 + 0] = i0;
      idxL[g * 3 + 1] = i1;
      idxL[g * 3 + 2] = i2;
      wL[g * 3 + 0] = r0 * s;
      wL[g * 3 + 1] = r1 * s;
      wL[g * 3 + 2] = r2 * s;
    }
  }
  __syncthreads();  // all xs4 reads done before build overwrites As

  // ---- build phase: As[t][row][kk], elem off = t*1024 + row*32 + kk ----
#pragma unroll 4
  for (int it = 0; it < 8; ++it) {
    int rl = wave * 8 + it;
    int row = row0 + rl;
    int i0 = idxL[rl * 3 + 0], i1 = idxL[rl * 3 + 1], i2 = idxL[rl * 3 + 2];
    float w0 = wL[rl * 3 + 0], w1 = wL[rl * 3 + 1], w2 = wL[rl * 3 + 2];

    const float4* f0 = (const float4*)(feat2 + ((size_t)b * N2_ + i0) * C2_);
    const float4* f1 = (const float4*)(feat2 + ((size_t)b * N2_ + i1) * C2_);
    const float4* f2 = (const float4*)(feat2 + ((size_t)b * N2_ + i2) * C2_);
    float4 a = f0[lane];
    float4 c = f1[lane];
    float4 d = f2[lane];
    float vx = w0 * a.x + w1 * c.x + w2 * d.x;
    float vy = w0 * a.y + w1 * c.y + w2 * d.y;
    float vz = w0 * a.z + w1 * c.z + w2 * d.z;
    float vw = w0 * a.w + w1 * c.w + w2 * d.w;
    // cols 4*lane .. 4*lane+3 (never straddle a 32-col tile)
    uint_t lo = (uint_t)f2bf(vx) | ((uint_t)f2bf(vy) << 16);
    uint_t hi = (uint_t)f2bf(vz) | ((uint_t)f2bf(vw) << 16);
    int e = (lane >> 3) * 1024 + rl * 32 + ((4 * lane) & 31);
    *(uint2*)&As[e] = make_uint2(lo, hi);

    // feat1: cols 256 + 2*lane, 2*lane+1
    float2 t1 = ((const float2*)(feat1 + (size_t)row * C1_))[lane];
    uint_t pk = (uint_t)f2bf(t1.x) | ((uint_t)f2bf(t1.y) << 16);
    int e1 = (8 + (lane >> 4)) * 1024 + rl * 32 + ((2 * lane) & 31);
    *(uint_t*)&As[e1] = pk;
  }
  __syncthreads();

  // ---- GEMM1: acc[32 rows][64 cols per wave], K = 384, no barriers ----
  const int b_off = (wave * 64 + m) * 32 + q * 8;  // frag base in W1s/W2s tile
  const int a_base = m * 32 + q * 8;

  floatx4 acc[2][4];
#pragma unroll
  for (int i = 0; i < 2; ++i)
#pragma unroll
    for (int j = 0; j < 4; ++j) acc[i][j] = (floatx4)0.0f;

  {
    bf16x8 bf0[4], bf1[4], af[2];
#pragma unroll
    for (int j = 0; j < 4; ++j)
      bf0[j] = *(const bf16x8*)(W1s + b_off + j * 512);
#pragma unroll
    for (int t = 0; t < 12; t += 2) {
#pragma unroll
      for (int j = 0; j < 4; ++j)
        bf1[j] = *(const bf16x8*)(W1s + (size_t)(t + 1) * 8192 + b_off + j * 512);
#pragma unroll
      for (int i = 0; i < 2; ++i)
        af[i] = *(const bf16x8*)&As[t * 1024 + a_base + i * 512];
#pragma unroll
      for (int i = 0; i < 2; ++i)
#pragma unroll
        for (int j = 0; j < 4; ++j)
          acc[i][j] = __builtin_amdgcn_mfma_f32_16x16x32_bf16(af[i], bf0[j],
                                                              acc[i][j], 0, 0, 0);
      if (t + 2 < 12) {
#pragma unroll
        for (int j = 0; j < 4; ++j)
          bf0[j] = *(const bf16x8*)(W1s + (size_t)(t + 2) * 8192 + b_off + j * 512);
      }
#pragma unroll
      for (int i = 0; i < 2; ++i)
        af[i] = *(const bf16x8*)&As[(t + 1) * 1024 + a_base + i * 512];
#pragma unroll
      for (int i = 0; i < 2; ++i)
#pragma unroll
        for (int j = 0; j < 4; ++j)
          acc[i][j] = __builtin_amdgcn_mfma_f32_16x16x32_bf16(af[i], bf1[j],
                                                              acc[i][j], 0, 0, 0);
    }
  }
  __syncthreads();  // all As reads done before HS overwrites the region

  // ---- epilogue1: bias + relu -> bf16 HS (aliases As; XOR-chunk swizzle) ----
  ushort_t* HS = As;  // 32 x 256 = 8192 elems = 16 KB
#pragma unroll
  for (int j = 0; j < 4; ++j) {
    int col = wave * 64 + j * 16 + m;
    float bv = b1[col];
    int cb = (col >> 3) & 3;
    int tb = (col >> 5) * 1024 + (col & 7);
#pragma unroll
    for (int i = 0; i < 2; ++i)
#pragma unroll
      for (int r = 0; r < 4; ++r) {
        int row = i * 16 + q * 4 + r;
        float v = acc[i][j][r] + bv;
        v = v > 0.0f ? v : 0.0f;
        int ch = cb ^ ((row >> 2) & 3);
        HS[tb + row * 32 + ch * 8] = f2bf(v);
      }
  }
  __syncthreads();

  // ---- GEMM2: K = 256, a-frags from HS, no barriers ----
  floatx4 acc2[2][4];
#pragma unroll
  for (int i = 0; i < 2; ++i)
#pragma unroll
    for (int j = 0; j < 4; ++j) acc2[i][j] = (floatx4)0.0f;

  {
    bf16x8 bf0[4], bf1[4], af[2];
#pragma unroll
    for (int j = 0; j < 4; ++j)
      bf0[j] = *(const bf16x8*)(W2s + b_off + j * 512);
#pragma unroll
    for (int t = 0; t < 8; t += 2) {
#pragma unroll
      for (int j = 0; j < 4; ++j)
        bf1[j] = *(const bf16x8*)(W2s + (size_t)(t + 1) * 8192 + b_off + j * 512);
#pragma unroll
      for (int i = 0; i < 2; ++i) {
        int row = m + 16 * i;
        int ch = q ^ ((row >> 2) & 3);
        af[i] = *(const bf16x8*)&HS[t * 1024 + row * 32 + ch * 8];
      }
#pragma unroll
      for (int i = 0; i < 2; ++i)
#pragma unroll
        for (int j = 0; j < 4; ++j)
          acc2[i][j] = __builtin_amdgcn_mfma_f32_16x16x32_bf16(af[i], bf0[j],
                                                               acc2[i][j], 0, 0, 0);
      if (t + 2 < 8) {
#pragma unroll
        for (int j = 0; j < 4; ++j)
          bf0[j] = *(const bf16x8*)(W2s + (size_t)(t + 2) * 8192 + b_off + j * 512);
      }
#pragma unroll
      for (int i = 0; i < 2; ++i) {
        int row = m + 16 * i;
        int ch = q ^ ((row >> 2) & 3);
        af[i] = *(const bf16x8*)&HS[(t + 1) * 1024 + row * 32 + ch * 8];
      }
#pragma unroll
      for (int i = 0; i < 2; ++i)
#pragma unroll
        for (int j = 0; j < 4; ++j)
          acc2[i][j] = __builtin_amdgcn_mfma_f32_16x16x32_bf16(af[i], bf1[j],
                                                               acc2[i][j], 0, 0, 0);
    }
  }

  // ---- epilogue2: bias + relu -> fp32 out ----
#pragma unroll
  for (int j = 0; j < 4; ++j) {
    int col = wave * 64 + j * 16 + m;
    float bv = b2[col];
#pragma unroll
    for (int i = 0; i < 2; ++i)
#pragma unroll
      for (int r = 0; r < 4; ++r) {
        int row = i * 16 + q * 4 + r;
        float v = acc2[i][j][r] + bv;
        v = v > 0.0f ? v : 0.0f;
        out[(size_t)(row0 + row) * DOUT_ + col] = v;
      }
  }
}

// ---------------- workspace layout ----------------

constexpr size_t OFF_W1S = 0;                  // 256*384*2 = 196608
constexpr size_t OFF_W2S = OFF_W1S + 196608;   // 256*256*2 = 131072
constexpr size_t WS_TOTAL = OFF_W2S + 131072;  // 320 KB

extern "C" void kernel_launch(void* const* d_in, const int* in_sizes, int n_in,
                              void* d_out, int out_size, void* d_ws, size_t ws_size,
                              hipStream_t stream) {
  const float* xyz1 = (const float*)d_in[0];
  const float* feat1 = (const float*)d_in[1];
  const float* xyz2 = (const float*)d_in[2];
  const float* feat2 = (const float*)d_in[3];
  const float* W1 = (const float*)d_in[4];
  const float* b1 = (const float*)d_in[5];
  const float* W2 = (const float*)d_in[6];
  const float* b2 = (const float*)d_in[7];

  if (ws_size < WS_TOTAL) return;

  char* ws = (char*)d_ws;
  ushort_t* W1s = (ushort_t*)(ws + OFF_W1S);
  ushort_t* W2s = (ushort_t*)(ws + OFF_W2S);

  prep_kernel<<<384, 256, 0, stream>>>(W1, W2, W1s, W2s);
  fused_kernel<<<M_ / 32, 256, 0, stream>>>(xyz1, xyz2, feat1, feat2, W1s, b1,
                                            W2s, b2, (float*)d_out);
}